// Round 16
// baseline (241.318 us; speedup 1.0000x reference)
//
#include <hip/hip_runtime.h>

#define N_NODES 100000
#define N_EDGES 1200000
#define CH 64
#define NG 256
#define OC 8
#define NBUK 196        // ceil(N_NODES/512)
#define BINCHUNK 4096
#define NBLKA 293       // ceil(N_EDGES/BINCHUNK)
#define NSTRIP 6250     // N_NODES/16 (exact)
#define ZERO_U4 4160    // (65536+1024)/16 : gsum+gcnt

typedef unsigned short ushort_t;
typedef unsigned int uint_t;
typedef __attribute__((ext_vector_type(8))) short bf16x8;
typedef __attribute__((ext_vector_type(4))) float f32x4;

__device__ __forceinline__ ushort_t f2bf(float f) {  // RNE f32->bf16
  uint_t u = __float_as_uint(f);
  return (ushort_t)((u + 0x7FFFu + ((u >> 16) & 1u)) >> 16);
}
__device__ __forceinline__ float bf2f(ushort_t b) {
  return __uint_as_float(((uint_t)b) << 16);
}

// ---------------- fused prep + countA ----------------
// All blocks: zero gsum/gcnt slice + per-block partial histogram (no global
// atomics, no gbase memset race). Block 0 additionally converts W -> bf16.
__global__ __launch_bounds__(256) void prepcount_k(
    const int* __restrict__ dst, const float* __restrict__ W1l,
    const float* __restrict__ W1r, const float* __restrict__ W2l,
    const float* __restrict__ W2r, ushort_t* __restrict__ wb,
    uint4* __restrict__ zr, int* __restrict__ pbh) {
  const int gi = blockIdx.x * blockDim.x + threadIdx.x;
  for (int i = gi; i < ZERO_U4; i += gridDim.x * blockDim.x)
    zr[i] = make_uint4(0, 0, 0, 0);
  __shared__ int hist[NBUK];
  for (int i = threadIdx.x; i < NBUK; i += 256) hist[i] = 0;
  __syncthreads();
  const int cs = blockIdx.x * BINCHUNK;
  int ce = cs + BINCHUNK;
  if (ce > N_EDGES) ce = N_EDGES;
  for (int e = cs + threadIdx.x; e < ce; e += 256)
    atomicAdd(&hist[dst[e] >> 9], 1);
  __syncthreads();
  for (int b = threadIdx.x; b < NBUK; b += 256)
    pbh[blockIdx.x * NBUK + b] = hist[b];
  if (blockIdx.x == 0) {
    for (int k = threadIdx.x; k < CH * CH; k += 256) {
      wb[k]               = f2bf(W1l[k]);
      wb[k + CH * CH]     = f2bf(W1r[k]);
      wb[k + 2 * CH * CH] = f2bf(W2l[k]);
      wb[k + 3 * CH * CH] = f2bf(W2r[k]);
    }
  }
}

// ---------------- pass B: column-sum partials, exclusive scan -> boff/cursor ----
__global__ void scanB_k(const int* __restrict__ pbh, int* __restrict__ boff,
                        int* __restrict__ cursor) {
  __shared__ int s[256];
  int v = 0;
  if (threadIdx.x < NBUK)
    for (int b = 0; b < NBLKA; ++b) v += pbh[b * NBUK + threadIdx.x];
  s[threadIdx.x] = v;
  __syncthreads();
  for (int o = 1; o < 256; o <<= 1) {
    int t = (threadIdx.x >= o) ? s[threadIdx.x - o] : 0;
    __syncthreads();
    s[threadIdx.x] += t;
    __syncthreads();
  }
  if (threadIdx.x < NBUK) {
    int ex = s[threadIdx.x] - v;
    boff[threadIdx.x] = ex;
    cursor[threadIdx.x] = ex;
  }
  if (threadIdx.x == NBUK - 1) boff[NBUK] = s[threadIdx.x];
}

// ---------------- pass A2: scatter packed edges into bucket regions ----------------
__global__ __launch_bounds__(256) void scatterA_k(const int* __restrict__ src,
                                                  const int* __restrict__ dst,
                                                  int* __restrict__ cursor,
                                                  int* __restrict__ tmp) {
  __shared__ int hist[NBUK];
  for (int i = threadIdx.x; i < NBUK; i += 256) hist[i] = 0;
  __syncthreads();
  const int cs = blockIdx.x * BINCHUNK;
  int ce = cs + BINCHUNK;
  if (ce > N_EDGES) ce = N_EDGES;
  for (int e = cs + threadIdx.x; e < ce; e += 256)
    atomicAdd(&hist[dst[e] >> 9], 1);
  __syncthreads();
  for (int b = threadIdx.x; b < NBUK; b += 256) {
    int c = hist[b];
    hist[b] = c ? atomicAdd(&cursor[b], c) : 0;
  }
  __syncthreads();
  for (int e = cs + threadIdx.x; e < ce; e += 256) {
    int d = dst[e];
    int slot = atomicAdd(&hist[d >> 9], 1);
    tmp[slot] = (src[e] << 9) | (d & 511);
  }
}

// ---------------- pass C: per-bucket fine CSR (rowptr + col) ----------------
// col stores src*CH (pre-scaled row offset).
__global__ __launch_bounds__(512) void csrC_k(const int* __restrict__ tmp,
                                              const int* __restrict__ boff,
                                              int* __restrict__ rp,
                                              int* __restrict__ col) {
  __shared__ int lh[512];
  __shared__ int s[512];
  const int b = blockIdx.x;
  const int tid = threadIdx.x;
  const int eb = boff[b], ee = boff[b + 1];
  lh[tid] = 0;
  __syncthreads();
  for (int e = eb + tid; e < ee; e += 512) atomicAdd(&lh[tmp[e] & 511], 1);
  __syncthreads();
  int v = lh[tid];
  s[tid] = v;
  __syncthreads();
  for (int o = 1; o < 512; o <<= 1) {
    int t = (tid >= o) ? s[tid - o] : 0;
    __syncthreads();
    s[tid] += t;
    __syncthreads();
  }
  const int base = eb + s[tid] - v;
  const int node = b * 512 + tid;
  if (node < N_NODES) rp[node] = base;
  if (b == 0 && tid == 0) rp[N_NODES] = N_EDGES;
  lh[tid] = base;
  __syncthreads();
  for (int e = eb + tid; e < ee; e += 512) {
    int p = tmp[e];
    int slot = atomicAdd(&lh[p & 511], 1);
    col[slot] = (p >> 9) * CH;
  }
}

// ---------------- MFMA dual transform: outl/outr (bf16) = in@Wl^T / in@Wr^T ----
// TIN = float (layer 1) or ushort_t (layer 2).
// C/D mapping: col=lane&15, row=(lane>>4)*4+reg  [m89-verified].
template <typename TIN>
__global__ __launch_bounds__(256) void transform_mfma_k(
    const TIN* __restrict__ in, const ushort_t* __restrict__ Wlb,
    const ushort_t* __restrict__ Wrb, ushort_t* __restrict__ outl,
    ushort_t* __restrict__ outr) {
  const int wid = blockIdx.x * 4 + (threadIdx.x >> 6);
  if (wid >= NSTRIP) return;
  const int lane = threadIdx.x & 63;
  const int row = lane & 15;
  const int kb = lane >> 4;  // k-block 0..3 (8 contiguous k each)

  bf16x8 Bfrag[8][2];
#pragma unroll
  for (int t = 0; t < 8; ++t) {
    const ushort_t* W = (t < 4) ? Wlb : Wrb;
    const int j = (t & 3) * 16 + row;
#pragma unroll
    for (int h = 0; h < 2; ++h)
      Bfrag[t][h] = *(const bf16x8*)(W + j * CH + h * 32 + kb * 8);
  }

  const int n0 = wid * 16;
  bf16x8 Afrag[2];
#pragma unroll
  for (int h = 0; h < 2; ++h) {
    if constexpr (sizeof(TIN) == 4) {
      const float* p = (const float*)in + (size_t)(n0 + row) * CH + h * 32 + kb * 8;
      float4 a0 = *(const float4*)p;
      float4 a1 = *(const float4*)(p + 4);
      bf16x8 a;
      a[0] = (short)f2bf(a0.x); a[1] = (short)f2bf(a0.y);
      a[2] = (short)f2bf(a0.z); a[3] = (short)f2bf(a0.w);
      a[4] = (short)f2bf(a1.x); a[5] = (short)f2bf(a1.y);
      a[6] = (short)f2bf(a1.z); a[7] = (short)f2bf(a1.w);
      Afrag[h] = a;
    } else {
      const ushort_t* p =
          (const ushort_t*)in + (size_t)(n0 + row) * CH + h * 32 + kb * 8;
      Afrag[h] = *(const bf16x8*)p;
    }
  }

  f32x4 acc[8];
#pragma unroll
  for (int t = 0; t < 8; ++t) {
    acc[t] = (f32x4){0.f, 0.f, 0.f, 0.f};
    acc[t] = __builtin_amdgcn_mfma_f32_16x16x32_bf16(Afrag[0], Bfrag[t][0],
                                                     acc[t], 0, 0, 0);
    acc[t] = __builtin_amdgcn_mfma_f32_16x16x32_bf16(Afrag[1], Bfrag[t][1],
                                                     acc[t], 0, 0, 0);
  }

  const int orow = (lane >> 4) * 4;
#pragma unroll
  for (int t = 0; t < 4; ++t)
#pragma unroll
    for (int i = 0; i < 4; ++i)
      outl[(size_t)(n0 + orow + i) * CH + t * 16 + row] = f2bf(acc[t][i]);
#pragma unroll
  for (int t = 4; t < 8; ++t)
#pragma unroll
    for (int i = 0; i < 4; ++i)
      outr[(size_t)(n0 + orow + i) * CH + (t - 4) * 16 + row] = f2bf(acc[t][i]);
}

// ---------------- gather(bf16) + mean + bias + relu (+ optional pool) ----------------
// R12 structure (proven 50µs floor): 8 independent chains, lane = channel.
// Streaming traffic (col, gr, outh) is non-temporal; random gl reads cached.
template <int MODE>
__global__ __launch_bounds__(256) void gather_k(
    const ushort_t* __restrict__ gl, const ushort_t* __restrict__ gr,
    const float* __restrict__ bl, const int* __restrict__ rowptr,
    const int* __restrict__ col, ushort_t* __restrict__ outh,
    const int* __restrict__ batch, float* __restrict__ gsum,
    int* __restrict__ gcnt) {
  const int lane = threadIdx.x & 63;
  const float biasv = bl[lane];
  const int wid = blockIdx.x * (blockDim.x >> 6) + (threadIdx.x >> 6);
  const int nw = gridDim.x * (blockDim.x >> 6);
  const int per = (N_NODES + nw - 1) / nw;
  int ns = wid * per;
  int ne = ns + per;
  if (ne > N_NODES) ne = N_NODES;
  if (ns >= ne) return;

  int curg = -1;
  float paccv = 0.f;
  int pcnt = 0;

  for (int n = ns; n < ne; ++n) {
    const int eb = rowptr[n], ee = rowptr[n + 1];
    float a0 = 0.f, a1 = 0.f, a2 = 0.f, a3 = 0.f;
    float a4 = 0.f, a5 = 0.f, a6 = 0.f, a7 = 0.f;
    int i = eb;
    for (; i + 8 <= ee; i += 8) {
      int c0 = __builtin_nontemporal_load(&col[i]);
      int c1 = __builtin_nontemporal_load(&col[i + 1]);
      int c2 = __builtin_nontemporal_load(&col[i + 2]);
      int c3 = __builtin_nontemporal_load(&col[i + 3]);
      int c4 = __builtin_nontemporal_load(&col[i + 4]);
      int c5 = __builtin_nontemporal_load(&col[i + 5]);
      int c6 = __builtin_nontemporal_load(&col[i + 6]);
      int c7 = __builtin_nontemporal_load(&col[i + 7]);
      a0 += bf2f(gl[(size_t)c0 + lane]);
      a1 += bf2f(gl[(size_t)c1 + lane]);
      a2 += bf2f(gl[(size_t)c2 + lane]);
      a3 += bf2f(gl[(size_t)c3 + lane]);
      a4 += bf2f(gl[(size_t)c4 + lane]);
      a5 += bf2f(gl[(size_t)c5 + lane]);
      a6 += bf2f(gl[(size_t)c6 + lane]);
      a7 += bf2f(gl[(size_t)c7 + lane]);
    }
    for (; i + 4 <= ee; i += 4) {
      int c0 = __builtin_nontemporal_load(&col[i]);
      int c1 = __builtin_nontemporal_load(&col[i + 1]);
      int c2 = __builtin_nontemporal_load(&col[i + 2]);
      int c3 = __builtin_nontemporal_load(&col[i + 3]);
      a0 += bf2f(gl[(size_t)c0 + lane]);
      a1 += bf2f(gl[(size_t)c1 + lane]);
      a2 += bf2f(gl[(size_t)c2 + lane]);
      a3 += bf2f(gl[(size_t)c3 + lane]);
    }
    for (; i < ee; ++i)
      a0 += bf2f(gl[(size_t)__builtin_nontemporal_load(&col[i]) + lane]);
    const int deg = ee - eb;
    const float inv = deg > 0 ? 1.f / (float)deg : 1.f;
    const float s = ((a0 + a1) + (a2 + a3)) + ((a4 + a5) + (a6 + a7));
    const ushort_t gv = __builtin_nontemporal_load(&gr[(size_t)n * CH + lane]);
    const float r = fmaxf(fmaf(s, inv, biasv + bf2f(gv)), 0.f);
    if (MODE == 0) {
      __builtin_nontemporal_store(f2bf(r), &outh[(size_t)n * CH + lane]);
    } else {
      int g = batch[n];
      if (g != curg) {
        if (curg >= 0) {
          atomicAdd(&gsum[curg * CH + lane], paccv);
          if (lane == 0) atomicAdd(&gcnt[curg], pcnt);
        }
        curg = g;
        paccv = 0.f;
        pcnt = 0;
      }
      paccv += r;
      pcnt++;
    }
  }
  if (MODE == 1 && curg >= 0) {
    atomicAdd(&gsum[curg * CH + lane], paccv);
    if (lane == 0) atomicAdd(&gcnt[curg], pcnt);
  }
}

// ---------------- final projection ----------------
__global__ void final_k(const float* __restrict__ gsum, const int* __restrict__ gcnt,
                        const float* __restrict__ Wc, const float* __restrict__ bc,
                        float* __restrict__ out) {
  __shared__ float Wcs[OC * CH];
  __shared__ float bcs[OC];
  for (int i = threadIdx.x; i < OC * CH; i += blockDim.x) Wcs[i] = Wc[i];
  if (threadIdx.x < OC) bcs[threadIdx.x] = bc[threadIdx.x];
  __syncthreads();
  int g = threadIdx.x;
  float c = (float)gcnt[g];
  float inv = c > 0.f ? 1.f / c : 1.f;
  float gr[CH];
#pragma unroll
  for (int k = 0; k < CH; ++k) gr[k] = gsum[g * CH + k] * inv;
#pragma unroll
  for (int o = 0; o < OC; ++o) {
    float acc = bcs[o];
#pragma unroll
    for (int k = 0; k < CH; ++k) acc += gr[k] * Wcs[o * CH + k];
    out[g * OC + o] = acc;
  }
}

extern "C" void kernel_launch(void* const* d_in, const int* in_sizes, int n_in,
                              void* d_out, int out_size, void* d_ws, size_t ws_size,
                              hipStream_t stream) {
  const float* x   = (const float*)d_in[0];
  const int*   ei  = (const int*)d_in[1];
  const int*   bat = (const int*)d_in[2];
  const float* W1l = (const float*)d_in[3];
  const float* b1l = (const float*)d_in[4];
  const float* W1r = (const float*)d_in[5];
  const float* W2l = (const float*)d_in[6];
  const float* b2l = (const float*)d_in[7];
  const float* W2r = (const float*)d_in[8];
  const float* Wc  = (const float*)d_in[9];
  const float* bc  = (const float*)d_in[10];
  float* out = (float*)d_out;

  char* ws = (char*)d_ws;
  // row-major bf16 node buffers (12.8MB each):
  //   buf1: xl -> h2l     buf3: h1     buf2: xr -> h2r
  ushort_t* buf1 = (ushort_t*)(ws + 0);         // 12,800,000 B
  ushort_t* buf3 = (ushort_t*)(ws + 12800000);  // 12,800,000 B
  ushort_t* buf2 = (ushort_t*)(ws + 25600000);  // 12,800,000 B
  int*   tmp     = (int*)(ws + 0);              //  4,800,000 B (aliased w/ buf1; CSR phase only)
  int*   pbh     = (int*)(ws + 6400000);        //    229,712 B (aliased w/ buf1; CSR phase only)
  int*   rp      = (int*)(ws + 51200000);       //    400,128 B (incl pad)
  int*   col     = (int*)(ws + 51600128);       //  4,800,000 B
  // contiguous zero region: gsum + gcnt (66,560 B)
  float* gsum    = (float*)(ws + 56400128);     //     65,536 B
  int*   gcnt    = (int*)(ws + 56465664);       //      1,024 B
  int*   boff    = (int*)(ws + 56467712);       //      1,024 B
  int*   cursor  = (int*)(ws + 56468736);       //      1,024 B
  ushort_t* wbf  = (ushort_t*)(ws + 56469760);  //     32,768 B (4x 64x64 bf16)

  const int* src = ei;
  const int* dst = ei + N_EDGES;

  // ---- fused prep+count, scan, scatter, fine-CSR ----
  prepcount_k<<<NBLKA, 256, 0, stream>>>(dst, W1l, W1r, W2l, W2r, wbf,
                                         (uint4*)(ws + 56400128), pbh);
  scanB_k<<<1, 256, 0, stream>>>(pbh, boff, cursor);
  scatterA_k<<<NBLKA, 256, 0, stream>>>(src, dst, cursor, tmp);
  csrC_k<<<NBUK, 512, 0, stream>>>(tmp, boff, rp, col);

  // ---- layer 1: x(f32) -> xl(buf1), xr(buf2); gather -> h1(buf3) ----
  transform_mfma_k<float><<<(NSTRIP + 3) / 4, 256, 0, stream>>>(
      x, wbf, wbf + CH * CH, buf1, buf2);
  gather_k<0><<<2048, 256, 0, stream>>>(buf1, buf2, b1l, rp, col, buf3,
                                        nullptr, nullptr, nullptr);
  // ---- layer 2: h1(buf3) -> h2l(buf1), h2r(buf2); gather+pool ----
  transform_mfma_k<ushort_t><<<(NSTRIP + 3) / 4, 256, 0, stream>>>(
      buf3, wbf + 2 * CH * CH, wbf + 3 * CH * CH, buf1, buf2);
  gather_k<1><<<2048, 256, 0, stream>>>(buf1, buf2, b2l, rp, col, nullptr,
                                        bat, gsum, gcnt);
  // ---- classify ----
  final_k<<<1, 256, 0, stream>>>(gsum, gcnt, Wc, bc, out);
}

// Round 17
// 203.045 us; speedup vs baseline: 1.1885x; 1.1885x over previous
//
#include <hip/hip_runtime.h>

#define N_NODES 100000
#define N_EDGES 1200000
#define CH 64
#define NG 256
#define OC 8
#define NBUK 196        // ceil(N_NODES/512)
#define BINCHUNK 4096
#define NBLKA 293       // ceil(N_EDGES/BINCHUNK)
#define NSTRIP 6250     // N_NODES/16 (exact)
#define ZERO_U4 4224    // (65536+1024+1024)/16 : gsum+gcnt+gbase

typedef unsigned short ushort_t;
typedef unsigned int uint_t;
typedef __attribute__((ext_vector_type(8))) short bf16x8;
typedef __attribute__((ext_vector_type(4))) float f32x4;

__device__ __forceinline__ ushort_t f2bf(float f) {  // RNE f32->bf16
  uint_t u = __float_as_uint(f);
  return (ushort_t)((u + 0x7FFFu + ((u >> 16) & 1u)) >> 16);
}
__device__ __forceinline__ float bf2f(ushort_t b) {
  return __uint_as_float(((uint_t)b) << 16);
}

// ---------------- prep: W -> bf16 + zero accumulators (replaces 3 memsets) ----
__global__ void prep_k(const float* __restrict__ W1l, const float* __restrict__ W1r,
                       const float* __restrict__ W2l, const float* __restrict__ W2r,
                       ushort_t* __restrict__ wb, uint4* __restrict__ zr) {
  const int gi = blockIdx.x * blockDim.x + threadIdx.x;
  for (int i = gi; i < ZERO_U4; i += gridDim.x * blockDim.x)
    zr[i] = make_uint4(0, 0, 0, 0);
  if (blockIdx.x == 0) {
    for (int k = threadIdx.x; k < CH * CH; k += 256) {
      wb[k]               = f2bf(W1l[k]);
      wb[k + CH * CH]     = f2bf(W1r[k]);
      wb[k + 2 * CH * CH] = f2bf(W2l[k]);
      wb[k + 3 * CH * CH] = f2bf(W2r[k]);
    }
  }
}

// ---------------- pass A1: per-bucket totals (dst>>9) ----------------
__global__ __launch_bounds__(256) void countA_k(const int* __restrict__ dst,
                                                int* __restrict__ gbase) {
  __shared__ int hist[NBUK];
  for (int i = threadIdx.x; i < NBUK; i += 256) hist[i] = 0;
  __syncthreads();
  const int cs = blockIdx.x * BINCHUNK;
  int ce = cs + BINCHUNK;
  if (ce > N_EDGES) ce = N_EDGES;
  for (int e = cs + threadIdx.x; e < ce; e += 256)
    atomicAdd(&hist[dst[e] >> 9], 1);
  __syncthreads();
  for (int b = threadIdx.x; b < NBUK; b += 256) {
    int c = hist[b];
    if (c) atomicAdd(&gbase[b], c);
  }
}

// ---------------- pass B: exclusive scan -> boff; cursor = boff ----------------
__global__ void scanB_k(const int* __restrict__ gbase, int* __restrict__ boff,
                        int* __restrict__ cursor) {
  __shared__ int s[256];
  int v = (threadIdx.x < NBUK) ? gbase[threadIdx.x] : 0;
  s[threadIdx.x] = v;
  __syncthreads();
  for (int o = 1; o < 256; o <<= 1) {
    int t = (threadIdx.x >= o) ? s[threadIdx.x - o] : 0;
    __syncthreads();
    s[threadIdx.x] += t;
    __syncthreads();
  }
  if (threadIdx.x < NBUK) {
    int ex = s[threadIdx.x] - v;
    boff[threadIdx.x] = ex;
    cursor[threadIdx.x] = ex;
  }
  if (threadIdx.x == NBUK - 1) boff[NBUK] = s[threadIdx.x];
}

// ---------------- pass A2: scatter packed edges into bucket regions ----------------
__global__ __launch_bounds__(256) void scatterA_k(const int* __restrict__ src,
                                                  const int* __restrict__ dst,
                                                  int* __restrict__ cursor,
                                                  int* __restrict__ tmp) {
  __shared__ int hist[NBUK];
  for (int i = threadIdx.x; i < NBUK; i += 256) hist[i] = 0;
  __syncthreads();
  const int cs = blockIdx.x * BINCHUNK;
  int ce = cs + BINCHUNK;
  if (ce > N_EDGES) ce = N_EDGES;
  for (int e = cs + threadIdx.x; e < ce; e += 256)
    atomicAdd(&hist[dst[e] >> 9], 1);
  __syncthreads();
  for (int b = threadIdx.x; b < NBUK; b += 256) {
    int c = hist[b];
    hist[b] = c ? atomicAdd(&cursor[b], c) : 0;
  }
  __syncthreads();
  for (int e = cs + threadIdx.x; e < ce; e += 256) {
    int d = dst[e];
    int slot = atomicAdd(&hist[d >> 9], 1);
    tmp[slot] = (src[e] << 9) | (d & 511);
  }
}

// ---------------- pass C: per-bucket fine CSR (rowptr + col) ----------------
// col stores src*CH (pre-scaled row offset).
__global__ __launch_bounds__(512) void csrC_k(const int* __restrict__ tmp,
                                              const int* __restrict__ boff,
                                              int* __restrict__ rp,
                                              int* __restrict__ col) {
  __shared__ int lh[512];
  __shared__ int s[512];
  const int b = blockIdx.x;
  const int tid = threadIdx.x;
  const int eb = boff[b], ee = boff[b + 1];
  lh[tid] = 0;
  __syncthreads();
  for (int e = eb + tid; e < ee; e += 512) atomicAdd(&lh[tmp[e] & 511], 1);
  __syncthreads();
  int v = lh[tid];
  s[tid] = v;
  __syncthreads();
  for (int o = 1; o < 512; o <<= 1) {
    int t = (tid >= o) ? s[tid - o] : 0;
    __syncthreads();
    s[tid] += t;
    __syncthreads();
  }
  const int base = eb + s[tid] - v;
  const int node = b * 512 + tid;
  if (node < N_NODES) rp[node] = base;
  if (b == 0 && tid == 0) rp[N_NODES] = N_EDGES;
  lh[tid] = base;
  __syncthreads();
  for (int e = eb + tid; e < ee; e += 512) {
    int p = tmp[e];
    int slot = atomicAdd(&lh[p & 511], 1);
    col[slot] = (p >> 9) * CH;
  }
}

// ---------------- MFMA dual transform: outl/outr (bf16) = in@Wl^T / in@Wr^T ----
// TIN = float (layer 1) or ushort_t (layer 2).
// C/D mapping: col=lane&15, row=(lane>>4)*4+reg  [m89-verified].
template <typename TIN>
__global__ __launch_bounds__(256) void transform_mfma_k(
    const TIN* __restrict__ in, const ushort_t* __restrict__ Wlb,
    const ushort_t* __restrict__ Wrb, ushort_t* __restrict__ outl,
    ushort_t* __restrict__ outr) {
  const int wid = blockIdx.x * 4 + (threadIdx.x >> 6);
  if (wid >= NSTRIP) return;
  const int lane = threadIdx.x & 63;
  const int row = lane & 15;
  const int kb = lane >> 4;  // k-block 0..3 (8 contiguous k each)

  bf16x8 Bfrag[8][2];
#pragma unroll
  for (int t = 0; t < 8; ++t) {
    const ushort_t* W = (t < 4) ? Wlb : Wrb;
    const int j = (t & 3) * 16 + row;
#pragma unroll
    for (int h = 0; h < 2; ++h)
      Bfrag[t][h] = *(const bf16x8*)(W + j * CH + h * 32 + kb * 8);
  }

  const int n0 = wid * 16;
  bf16x8 Afrag[2];
#pragma unroll
  for (int h = 0; h < 2; ++h) {
    if constexpr (sizeof(TIN) == 4) {
      const float* p = (const float*)in + (size_t)(n0 + row) * CH + h * 32 + kb * 8;
      float4 a0 = *(const float4*)p;
      float4 a1 = *(const float4*)(p + 4);
      bf16x8 a;
      a[0] = (short)f2bf(a0.x); a[1] = (short)f2bf(a0.y);
      a[2] = (short)f2bf(a0.z); a[3] = (short)f2bf(a0.w);
      a[4] = (short)f2bf(a1.x); a[5] = (short)f2bf(a1.y);
      a[6] = (short)f2bf(a1.z); a[7] = (short)f2bf(a1.w);
      Afrag[h] = a;
    } else {
      const ushort_t* p =
          (const ushort_t*)in + (size_t)(n0 + row) * CH + h * 32 + kb * 8;
      Afrag[h] = *(const bf16x8*)p;
    }
  }

  f32x4 acc[8];
#pragma unroll
  for (int t = 0; t < 8; ++t) {
    acc[t] = (f32x4){0.f, 0.f, 0.f, 0.f};
    acc[t] = __builtin_amdgcn_mfma_f32_16x16x32_bf16(Afrag[0], Bfrag[t][0],
                                                     acc[t], 0, 0, 0);
    acc[t] = __builtin_amdgcn_mfma_f32_16x16x32_bf16(Afrag[1], Bfrag[t][1],
                                                     acc[t], 0, 0, 0);
  }

  const int orow = (lane >> 4) * 4;
#pragma unroll
  for (int t = 0; t < 4; ++t)
#pragma unroll
    for (int i = 0; i < 4; ++i)
      outl[(size_t)(n0 + orow + i) * CH + t * 16 + row] = f2bf(acc[t][i]);
#pragma unroll
  for (int t = 4; t < 8; ++t)
#pragma unroll
    for (int i = 0; i < 4; ++i)
      outr[(size_t)(n0 + orow + i) * CH + (t - 4) * 16 + row] = f2bf(acc[t][i]);
}

// ---------------- gather(bf16) + mean + bias + relu (+ optional pool) ----------------
// Proven-floor form (R12): 8 independent chains, lane = channel, cached col
// reads (wave-uniform, line-served), NT only on gr/outh streaming traffic.
template <int MODE>
__global__ __launch_bounds__(256) void gather_k(
    const ushort_t* __restrict__ gl, const ushort_t* __restrict__ gr,
    const float* __restrict__ bl, const int* __restrict__ rowptr,
    const int* __restrict__ col, ushort_t* __restrict__ outh,
    const int* __restrict__ batch, float* __restrict__ gsum,
    int* __restrict__ gcnt) {
  const int lane = threadIdx.x & 63;
  const float biasv = bl[lane];
  const int wid = blockIdx.x * (blockDim.x >> 6) + (threadIdx.x >> 6);
  const int nw = gridDim.x * (blockDim.x >> 6);
  const int per = (N_NODES + nw - 1) / nw;
  int ns = wid * per;
  int ne = ns + per;
  if (ne > N_NODES) ne = N_NODES;
  if (ns >= ne) return;

  int curg = -1;
  float paccv = 0.f;
  int pcnt = 0;

  for (int n = ns; n < ne; ++n) {
    const int eb = rowptr[n], ee = rowptr[n + 1];
    float a0 = 0.f, a1 = 0.f, a2 = 0.f, a3 = 0.f;
    float a4 = 0.f, a5 = 0.f, a6 = 0.f, a7 = 0.f;
    int i = eb;
    for (; i + 8 <= ee; i += 8) {
      int c0 = col[i],     c1 = col[i + 1], c2 = col[i + 2], c3 = col[i + 3];
      int c4 = col[i + 4], c5 = col[i + 5], c6 = col[i + 6], c7 = col[i + 7];
      a0 += bf2f(gl[(size_t)c0 + lane]);
      a1 += bf2f(gl[(size_t)c1 + lane]);
      a2 += bf2f(gl[(size_t)c2 + lane]);
      a3 += bf2f(gl[(size_t)c3 + lane]);
      a4 += bf2f(gl[(size_t)c4 + lane]);
      a5 += bf2f(gl[(size_t)c5 + lane]);
      a6 += bf2f(gl[(size_t)c6 + lane]);
      a7 += bf2f(gl[(size_t)c7 + lane]);
    }
    for (; i + 4 <= ee; i += 4) {
      int c0 = col[i], c1 = col[i + 1], c2 = col[i + 2], c3 = col[i + 3];
      a0 += bf2f(gl[(size_t)c0 + lane]);
      a1 += bf2f(gl[(size_t)c1 + lane]);
      a2 += bf2f(gl[(size_t)c2 + lane]);
      a3 += bf2f(gl[(size_t)c3 + lane]);
    }
    for (; i < ee; ++i) a0 += bf2f(gl[(size_t)col[i] + lane]);
    const int deg = ee - eb;
    const float inv = deg > 0 ? 1.f / (float)deg : 1.f;
    const float s = ((a0 + a1) + (a2 + a3)) + ((a4 + a5) + (a6 + a7));
    const ushort_t gv = __builtin_nontemporal_load(&gr[(size_t)n * CH + lane]);
    const float r = fmaxf(fmaf(s, inv, biasv + bf2f(gv)), 0.f);
    if (MODE == 0) {
      __builtin_nontemporal_store(f2bf(r), &outh[(size_t)n * CH + lane]);
    } else {
      int g = batch[n];
      if (g != curg) {
        if (curg >= 0) {
          atomicAdd(&gsum[curg * CH + lane], paccv);
          if (lane == 0) atomicAdd(&gcnt[curg], pcnt);
        }
        curg = g;
        paccv = 0.f;
        pcnt = 0;
      }
      paccv += r;
      pcnt++;
    }
  }
  if (MODE == 1 && curg >= 0) {
    atomicAdd(&gsum[curg * CH + lane], paccv);
    if (lane == 0) atomicAdd(&gcnt[curg], pcnt);
  }
}

// ---------------- final projection ----------------
__global__ void final_k(const float* __restrict__ gsum, const int* __restrict__ gcnt,
                        const float* __restrict__ Wc, const float* __restrict__ bc,
                        float* __restrict__ out) {
  __shared__ float Wcs[OC * CH];
  __shared__ float bcs[OC];
  for (int i = threadIdx.x; i < OC * CH; i += blockDim.x) Wcs[i] = Wc[i];
  if (threadIdx.x < OC) bcs[threadIdx.x] = bc[threadIdx.x];
  __syncthreads();
  int g = threadIdx.x;
  float c = (float)gcnt[g];
  float inv = c > 0.f ? 1.f / c : 1.f;
  float gr[CH];
#pragma unroll
  for (int k = 0; k < CH; ++k) gr[k] = gsum[g * CH + k] * inv;
#pragma unroll
  for (int o = 0; o < OC; ++o) {
    float acc = bcs[o];
#pragma unroll
    for (int k = 0; k < CH; ++k) acc += gr[k] * Wcs[o * CH + k];
    out[g * OC + o] = acc;
  }
}

extern "C" void kernel_launch(void* const* d_in, const int* in_sizes, int n_in,
                              void* d_out, int out_size, void* d_ws, size_t ws_size,
                              hipStream_t stream) {
  const float* x   = (const float*)d_in[0];
  const int*   ei  = (const int*)d_in[1];
  const int*   bat = (const int*)d_in[2];
  const float* W1l = (const float*)d_in[3];
  const float* b1l = (const float*)d_in[4];
  const float* W1r = (const float*)d_in[5];
  const float* W2l = (const float*)d_in[6];
  const float* b2l = (const float*)d_in[7];
  const float* W2r = (const float*)d_in[8];
  const float* Wc  = (const float*)d_in[9];
  const float* bc  = (const float*)d_in[10];
  float* out = (float*)d_out;

  char* ws = (char*)d_ws;
  // row-major bf16 node buffers (12.8MB each):
  //   buf1: xl -> h2l     buf3: h1     buf2: xr -> h2r
  ushort_t* buf1 = (ushort_t*)(ws + 0);         // 12,800,000 B
  ushort_t* buf3 = (ushort_t*)(ws + 12800000);  // 12,800,000 B
  ushort_t* buf2 = (ushort_t*)(ws + 25600000);  // 12,800,000 B
  int*   tmp     = (int*)(ws + 0);              //  4,800,000 B (aliased w/ buf1; CSR phase only)
  int*   rp      = (int*)(ws + 51200000);       //    400,128 B (incl pad)
  int*   col     = (int*)(ws + 51600128);       //  4,800,000 B
  // contiguous zero region: gsum + gcnt + gbase (67,584 B)
  float* gsum    = (float*)(ws + 56400128);     //     65,536 B
  int*   gcnt    = (int*)(ws + 56465664);       //      1,024 B
  int*   gbase   = (int*)(ws + 56466688);       //      1,024 B
  int*   boff    = (int*)(ws + 56467712);       //      1,024 B
  int*   cursor  = (int*)(ws + 56468736);       //      1,024 B
  ushort_t* wbf  = (ushort_t*)(ws + 56469760);  //     32,768 B (4x 64x64 bf16)

  const int* src = ei;
  const int* dst = ei + N_EDGES;

  // ---- prep (W->bf16 + zero gsum/gcnt/gbase) + CSR build ----
  prep_k<<<32, 256, 0, stream>>>(W1l, W1r, W2l, W2r, wbf,
                                 (uint4*)(ws + 56400128));
  countA_k<<<NBLKA, 256, 0, stream>>>(dst, gbase);
  scanB_k<<<1, 256, 0, stream>>>(gbase, boff, cursor);
  scatterA_k<<<NBLKA, 256, 0, stream>>>(src, dst, cursor, tmp);
  csrC_k<<<NBUK, 512, 0, stream>>>(tmp, boff, rp, col);

  // ---- layer 1: x(f32) -> xl(buf1), xr(buf2); gather -> h1(buf3) ----
  transform_mfma_k<float><<<(NSTRIP + 3) / 4, 256, 0, stream>>>(
      x, wbf, wbf + CH * CH, buf1, buf2);
  gather_k<0><<<2048, 256, 0, stream>>>(buf1, buf2, b1l, rp, col, buf3,
                                        nullptr, nullptr, nullptr);
  // ---- layer 2: h1(buf3) -> h2l(buf1), h2r(buf2); gather+pool ----
  transform_mfma_k<ushort_t><<<(NSTRIP + 3) / 4, 256, 0, stream>>>(
      buf3, wbf + 2 * CH * CH, wbf + 3 * CH * CH, buf1, buf2);
  gather_k<1><<<2048, 256, 0, stream>>>(buf1, buf2, b2l, rp, col, nullptr,
                                        bat, gsum, gcnt);
  // ---- classify ----
  final_k<<<1, 256, 0, stream>>>(gsum, gcnt, Wc, bc, out);
}